// Round 8
// baseline (562.427 us; speedup 1.0000x reference)
//
#include <hip/hip_runtime.h>

// AggregateSet fused kernel, MI355X (gfx950).
// Shapes: B=1024, M_ELEM=128, D_IN=64, D_HID=256, H=8, D_K=D_V=64.
// R7 = R6 schedule (one head per wave, single barrier, qk blocked over 2
// d-cols -> 4 MFMA per A-frag ds_read, v blocked over 4 d-cols) with the
// REGISTER CAP LIFTED: amdgpu_waves_per_eu(1). R6's failure mode: backend
// derived VGPR budget from LDS-limited occupancy (66KB -> 2 blocks/CU -> 4
// waves/EU -> 128-VGPR cap) and spilled 900MB/launch. waves_per_eu(1)
// allows up to 512 VGPRs; live set ~190 -> no spill, 2 waves/SIMD.
// K-perm identical for A/B frags (cancels inside MFMA).

typedef __attribute__((ext_vector_type(8))) short bf16x8;
typedef __attribute__((ext_vector_type(4))) float f32x4;

#define XROW 8320
#define MASK_OFF 8192

static __device__ __forceinline__ short f2bf(float f) {
  union { float f; unsigned u; } v; v.f = f;
  unsigned r = v.u + 0x7FFFu + ((v.u >> 16) & 1u);  // RNE
  return (short)(r >> 16);
}
static __device__ __forceinline__ f32x4 splat4(float v) {
  f32x4 r = {v, v, v, v};
  return r;
}

// ---------------------------------------------------------------------------
// Weight prep: fp32 row-major W[k][n] -> bf16 in MFMA FRAGMENT ORDER.
// Wsub (K=64,N=256):  idx = t*1024 + ks1*512 + lg*128 + l15*8 + j
//                     n = 16t+l15, k = 32ks1+8lg+j          (16384 shorts)
// Wq/Wk/Wv (K=256,N=512): idx = t*4096 + ks*512 + lg*128 + l15*8 + j
//                     n = 16t+l15, k = 32ks+8lg+j           (131072 each)
__global__ __launch_bounds__(256) void prep_weights(
    const float* __restrict__ Ws, const float* __restrict__ Wq,
    const float* __restrict__ Wk, const float* __restrict__ Wv,
    short* __restrict__ wt)
{
  __shared__ float lt[256 * 17];
  const int bid = blockIdx.x, tid = threadIdx.x;
  if (bid < 96) {
    const int m = bid >> 5, t = bid & 31;
    const float* W = (m == 0) ? Wq : (m == 1) ? Wk : Wv;
    #pragma unroll
    for (int rep = 0; rep < 16; ++rep) {
      int k = rep * 16 + (tid >> 4), n = tid & 15;
      lt[k * 17 + n] = W[k * 512 + 16 * t + n];
    }
    __syncthreads();
    bf16x8 o0, o1;
    const int ol = tid * 16;
    #pragma unroll
    for (int s = 0; s < 16; ++s) {
      int o = ol + s;
      int ks = (o >> 9) & 7, g2 = (o >> 7) & 3, n16 = (o >> 3) & 15, j = o & 7;
      int k = 32 * ks + 8 * g2 + j;
      short v = f2bf(lt[k * 17 + n16]);
      if (s < 8) o0[s] = v; else o1[s - 8] = v;
    }
    short* dst = wt + 16384 + m * 131072 + t * 4096 + ol;
    *(bf16x8*)dst = o0;
    *(bf16x8*)(dst + 8) = o1;
  } else {
    const int t = bid - 96;
    #pragma unroll
    for (int rep = 0; rep < 4; ++rep) {
      int k = rep * 16 + (tid >> 4), n = tid & 15;
      lt[k * 17 + n] = Ws[k * 256 + 16 * t + n];
    }
    __syncthreads();
    short4 o;
    const int ol = tid * 4;
    #pragma unroll
    for (int s = 0; s < 4; ++s) {
      int o_ = ol + s;
      int ks1 = (o_ >> 9) & 1, g2 = (o_ >> 7) & 3, n16 = (o_ >> 3) & 15, j = o_ & 7;
      int k = 32 * ks1 + 8 * g2 + j;
      short v = f2bf(lt[k * 17 + n16]);
      if (s == 0) o.x = v; else if (s == 1) o.y = v; else if (s == 2) o.z = v; else o.w = v;
    }
    *(short4*)(wt + t * 1024 + ol) = o;
  }
}

// A-frag (16x32) from swizzled shared activ: elem (e,k) at
// activ[e*256 + ((k>>3 ^ (e&15))<<3 | (k&7))]; frag k = 32ks+8lg+j.
static __device__ __forceinline__ bf16x8 ld_a(const short* activ,
                                              int e, int ks, int lg) {
  return *(const bf16x8*)(activ + e * 256 + ((((4 * ks + lg) ^ (e & 15))) << 3));
}

// qk for one mh half (rows 16*(4*MH+m4)+l15): 4 MFMA per A-frag load.
#define QK_MH(MH)                                                              \
  {                                                                            \
    f32x4 aq0[4], aq1[4], ak0[4], ak1[4];                                      \
    _Pragma("unroll") for (int i = 0; i < 4; ++i) {                            \
      aq0[i] = splat4(biq0); aq1[i] = splat4(biq1);                            \
      ak0[i] = splat4(bik0); ak1[i] = splat4(bik1);                            \
    }                                                                          \
    _Pragma("unroll") for (int ks = 0; ks < 8; ++ks) {                         \
      bf16x8 bqf0 = *(const bf16x8*)(baq0 + ks * 512);                         \
      bf16x8 bqf1 = *(const bf16x8*)(baq1 + ks * 512);                         \
      bf16x8 bkf0 = *(const bf16x8*)(bak0 + ks * 512);                         \
      bf16x8 bkf1 = *(const bf16x8*)(bak1 + ks * 512);                         \
      _Pragma("unroll") for (int m4 = 0; m4 < 4; ++m4) {                       \
        bf16x8 af = ld_a(activ, 16 * (4 * (MH) + m4) + l15, ks, lg);           \
        aq0[m4] = __builtin_amdgcn_mfma_f32_16x16x32_bf16(af, bqf0, aq0[m4], 0, 0, 0); \
        aq1[m4] = __builtin_amdgcn_mfma_f32_16x16x32_bf16(af, bqf1, aq1[m4], 0, 0, 0); \
        ak0[m4] = __builtin_amdgcn_mfma_f32_16x16x32_bf16(af, bkf0, ak0[m4], 0, 0, 0); \
        ak1[m4] = __builtin_amdgcn_mfma_f32_16x16x32_bf16(af, bkf1, ak1[m4], 0, 0, 0); \
      }                                                                        \
    }                                                                          \
    _Pragma("unroll") for (int m4 = 0; m4 < 4; ++m4)                           \
      _Pragma("unroll") for (int r = 0; r < 4; ++r)                            \
        pl[(4 * (MH) + m4) * 4 + r] +=                                         \
            aq0[m4][r] * ak0[m4][r] + aq1[m4][r] * ak1[m4][r];                 \
  }

// v for one mh half: all 4 d-cols at once, 4 MFMA per A-frag load.
#define V_MH(MH)                                                               \
  {                                                                            \
    f32x4 av0[4], av1[4], av2[4], av3[4];                                      \
    _Pragma("unroll") for (int i = 0; i < 4; ++i) {                            \
      av0[i] = splat4(biv0); av1[i] = splat4(biv1);                            \
      av2[i] = splat4(biv2); av3[i] = splat4(biv3);                            \
    }                                                                          \
    _Pragma("unroll") for (int ks = 0; ks < 8; ++ks) {                         \
      bf16x8 bvf0 = *(const bf16x8*)(bav0 + ks * 512);                         \
      bf16x8 bvf1 = *(const bf16x8*)(bav0 + 4096 + ks * 512);                  \
      bf16x8 bvf2 = *(const bf16x8*)(bav0 + 8192 + ks * 512);                  \
      bf16x8 bvf3 = *(const bf16x8*)(bav0 + 12288 + ks * 512);                 \
      _Pragma("unroll") for (int m4 = 0; m4 < 4; ++m4) {                       \
        bf16x8 af = ld_a(activ, 16 * (4 * (MH) + m4) + l15, ks, lg);           \
        av0[m4] = __builtin_amdgcn_mfma_f32_16x16x32_bf16(af, bvf0, av0[m4], 0, 0, 0); \
        av1[m4] = __builtin_amdgcn_mfma_f32_16x16x32_bf16(af, bvf1, av1[m4], 0, 0, 0); \
        av2[m4] = __builtin_amdgcn_mfma_f32_16x16x32_bf16(af, bvf2, av2[m4], 0, 0, 0); \
        av3[m4] = __builtin_amdgcn_mfma_f32_16x16x32_bf16(af, bvf3, av3[m4], 0, 0, 0); \
      }                                                                        \
    }                                                                          \
    _Pragma("unroll") for (int m4 = 0; m4 < 4; ++m4)                           \
      _Pragma("unroll") for (int r = 0; r < 4; ++r) {                          \
        float a = pl[(4 * (MH) + m4) * 4 + r];                                 \
        t0 += a * av0[m4][r]; t1 += a * av1[m4][r];                            \
        t2 += a * av2[m4][r]; t3 += a * av3[m4][r];                            \
      }                                                                        \
  }

__global__ __launch_bounds__(512)
__attribute__((amdgpu_waves_per_eu(1))) void fused_kernel(
    const float* __restrict__ x,
    const float* __restrict__ bsub, const float* __restrict__ bq,
    const float* __restrict__ bk,   const float* __restrict__ bv,
    const short* __restrict__ wt,   float* __restrict__ out)
{
  __shared__ short activ[128 * 256];   // 64KB, XOR-swizzled (16B granule)
  __shared__ float smask[128];

  const int b   = blockIdx.x;
  const int tid = threadIdx.x;
  const int w   = tid >> 6;       // wave 0..7  == head
  const int l   = tid & 63;
  const int l15 = l & 15;
  const int lg  = l >> 4;

  const float* xb  = x + (size_t)b * XROW;
  const short* wts = wt;
  const short* wtq = wt + 16384;
  const short* wtk = wtq + 131072;
  const short* wtv = wtk + 131072;

  if (tid < 128) smask[tid] = xb[MASK_OFF + tid];

  // ---------------- GEMM1: activ = xe @ Wsub + bsub ----------------------
  // wave w owns rows 16w..16w+15 (one m-tile).
  {
    bf16x8 a1[2];
    #pragma unroll
    for (int ks1 = 0; ks1 < 2; ++ks1) {
      int e = 16 * w + l15;
      const float* p = xb + e * 64 + 32 * ks1 + 8 * lg;
      float4 f0 = *(const float4*)p;
      float4 f1 = *(const float4*)(p + 4);
      bf16x8 t;
      t[0] = f2bf(f0.x); t[1] = f2bf(f0.y); t[2] = f2bf(f0.z); t[3] = f2bf(f0.w);
      t[4] = f2bf(f1.x); t[5] = f2bf(f1.y); t[6] = f2bf(f1.z); t[7] = f2bf(f1.w);
      a1[ks1] = t;
    }
    #pragma unroll 1
    for (int t = 0; t < 16; ++t) {
      f32x4 acc = splat4(bsub[16 * t + l15]);
      #pragma unroll
      for (int ks1 = 0; ks1 < 2; ++ks1) {
        bf16x8 bfw = *(const bf16x8*)(wts + t * 1024 + ks1 * 512 + lg * 128 + l15 * 8);
        acc = __builtin_amdgcn_mfma_f32_16x16x32_bf16(a1[ks1], bfw, acc, 0, 0, 0);
      }
      #pragma unroll
      for (int r = 0; r < 4; ++r) {
        int e   = 16 * w + 4 * lg + r;
        int col = 16 * t + l15;
        activ[e * 256 + ((((col >> 3) ^ (e & 15)) << 3) | (col & 7))] = f2bf(acc[r]);
      }
    }
  }
  __syncthreads();   // the only barrier

  // elem_frac (exact: mask is 0/1) — wave 0 lanes
  if (tid < 64) {
    float s = smask[tid] + smask[tid + 64];
    #pragma unroll
    for (int off = 32; off > 0; off >>= 1) s += __shfl_xor(s, off);
    if (tid == 0) out[b * 513 + 512] = s * (1.f / 128.f);
  }

  const int h = w;

  // lane's mask bits for its 32 rows e = 16mt + 4lg + r  (i = mt*4+r)
  unsigned mm = 0;
  #pragma unroll
  for (int mt = 0; mt < 8; ++mt)
    #pragma unroll
    for (int r = 0; r < 4; ++r)
      if (smask[16 * mt + 4 * lg + r] > 0.f) mm |= (1u << (mt * 4 + r));

  // ---------------- qk: scores for all 128 rows, this wave's head --------
  float pl[32];
  #pragma unroll
  for (int i = 0; i < 32; ++i) pl[i] = 0.f;

  #pragma unroll 1
  for (int ntp = 0; ntp < 2; ++ntp) {
    const short* baq0 = wtq + (4 * h + 2 * ntp) * 4096 + lg * 128 + l15 * 8;
    const short* baq1 = baq0 + 4096;
    const short* bak0 = wtk + (4 * h + 2 * ntp) * 4096 + lg * 128 + l15 * 8;
    const short* bak1 = bak0 + 4096;
    float biq0 = bq[h * 64 + 32 * ntp + l15];
    float biq1 = bq[h * 64 + 32 * ntp + 16 + l15];
    float bik0 = bk[h * 64 + 32 * ntp + l15];
    float bik1 = bk[h * 64 + 32 * ntp + 16 + l15];
    QK_MH(0)
    QK_MH(1)
  }
  // reduce d-partials over the 16 d-lanes; scale 1/sqrt(64)
  #pragma unroll
  for (int i = 0; i < 32; ++i) {
    float s = pl[i];
    s += __shfl_xor(s, 1);
    s += __shfl_xor(s, 2);
    s += __shfl_xor(s, 4);
    s += __shfl_xor(s, 8);
    pl[i] = s * 0.125f;
  }

  // ---------------- masked softmax, fully wave-local ----------------------
  float zmax = 0.f;  // relu floor
  #pragma unroll
  for (int i = 0; i < 32; ++i)
    zmax = fmaxf(zmax, ((mm >> i) & 1) ? pl[i] : 0.f);
  zmax = fmaxf(zmax, __shfl_xor(zmax, 16));
  zmax = fmaxf(zmax, __shfl_xor(zmax, 32));

  float esum = 0.f;
  #pragma unroll
  for (int i = 0; i < 32; ++i) {
    float ev = ((mm >> i) & 1) ? __expf(pl[i] - zmax) : 0.f;
    pl[i] = ev;
    esum += ev;
  }
  esum += __shfl_xor(esum, 16);
  esum += __shfl_xor(esum, 32);
  float inv = 1.f / (esum + 1.f);
  #pragma unroll
  for (int i = 0; i < 32; ++i) pl[i] *= inv;

  // ---------------- v: project + attn-weighted pool, direct out -----------
  {
    const short* bav0 = wtv + (4 * h) * 4096 + lg * 128 + l15 * 8;
    float biv0 = bv[h * 64 + l15];
    float biv1 = bv[h * 64 + 16 + l15];
    float biv2 = bv[h * 64 + 32 + l15];
    float biv3 = bv[h * 64 + 48 + l15];
    float t0 = 0.f, t1 = 0.f, t2 = 0.f, t3 = 0.f;
    V_MH(0)
    V_MH(1)
    t0 += __shfl_xor(t0, 16); t0 += __shfl_xor(t0, 32);
    t1 += __shfl_xor(t1, 16); t1 += __shfl_xor(t1, 32);
    t2 += __shfl_xor(t2, 16); t2 += __shfl_xor(t2, 32);
    t3 += __shfl_xor(t3, 16); t3 += __shfl_xor(t3, 32);
    if (lg == 0) {
      out[b * 513 + h * 64 + l15]      = t0;
      out[b * 513 + h * 64 + 16 + l15] = t1;
      out[b * 513 + h * 64 + 32 + l15] = t2;
      out[b * 513 + h * 64 + 48 + l15] = t3;
    }
  }
}

extern "C" void kernel_launch(void* const* d_in, const int* in_sizes, int n_in,
                              void* d_out, int out_size, void* d_ws, size_t ws_size,
                              hipStream_t stream) {
  (void)in_sizes; (void)n_in; (void)out_size; (void)ws_size;
  const float* x    = (const float*)d_in[0];
  const float* Wsub = (const float*)d_in[1];
  const float* bsub = (const float*)d_in[2];
  const float* Wq   = (const float*)d_in[3];
  const float* bq   = (const float*)d_in[4];
  const float* Wk   = (const float*)d_in[5];
  const float* bk   = (const float*)d_in[6];
  const float* Wv   = (const float*)d_in[7];
  const float* bv   = (const float*)d_in[8];
  float* out = (float*)d_out;
  short* wt  = (short*)d_ws;   // 800 KB used

  prep_weights<<<112, 256, 0, stream>>>(Wsub, Wq, Wk, Wv, wt);
  fused_kernel<<<1024, 512, 0, stream>>>(x, bsub, bq, bk, bv, wt, out);
}

// Round 9
// 473.294 us; speedup vs baseline: 1.1883x; 1.1883x over previous
//
#include <hip/hip_runtime.h>

// AggregateSet fused kernel, MI355X (gfx950).
// Shapes: B=1024, M_ELEM=128, D_IN=64, D_HID=256, H=8, D_K=D_V=64.
// R8 = R6 schedule (qk blocked over 2 d-cols -> 4 MFMA per A-frag ds_read;
// v blocked over 4 d-cols; weights in MFMA fragment order, read once per
// block; wave-local softmax; single barrier) but with 256-THREAD blocks:
// 4 waves, each wave runs TWO heads sequentially (h = w, w+4).
// Why: VGPR budget = 512-reg file / waves-per-SIMD implied by schedulable
// occupancy. 512-thr blocks + 64KB LDS => 4 waves/SIMD => hard 128-VGPR cap
// (R3/R4/R6/R7 evidence; attributes cannot lift it) and the R6 schedule
// needs ~140 live -> 900MB spills. 256-thr + (256,2) => 2 waves/SIMD =>
// 256-VGPR cap; R6's live set fits, reg headroom enables B-prefetch ILP.
// K-perm identical for A/B frags (cancels inside MFMA).

typedef __attribute__((ext_vector_type(8))) short bf16x8;
typedef __attribute__((ext_vector_type(4))) float f32x4;

#define XROW 8320
#define MASK_OFF 8192

static __device__ __forceinline__ short f2bf(float f) {
  union { float f; unsigned u; } v; v.f = f;
  unsigned r = v.u + 0x7FFFu + ((v.u >> 16) & 1u);  // RNE
  return (short)(r >> 16);
}
static __device__ __forceinline__ f32x4 splat4(float v) {
  f32x4 r = {v, v, v, v};
  return r;
}

// ---------------------------------------------------------------------------
// Weight prep: fp32 row-major W[k][n] -> bf16 in MFMA FRAGMENT ORDER.
// Wsub (K=64,N=256):  idx = t*1024 + ks1*512 + lg*128 + l15*8 + j
//                     n = 16t+l15, k = 32ks1+8lg+j          (16384 shorts)
// Wq/Wk/Wv (K=256,N=512): idx = t*4096 + ks*512 + lg*128 + l15*8 + j
//                     n = 16t+l15, k = 32ks+8lg+j           (131072 each)
__global__ __launch_bounds__(256) void prep_weights(
    const float* __restrict__ Ws, const float* __restrict__ Wq,
    const float* __restrict__ Wk, const float* __restrict__ Wv,
    short* __restrict__ wt)
{
  __shared__ float lt[256 * 17];
  const int bid = blockIdx.x, tid = threadIdx.x;
  if (bid < 96) {
    const int m = bid >> 5, t = bid & 31;
    const float* W = (m == 0) ? Wq : (m == 1) ? Wk : Wv;
    #pragma unroll
    for (int rep = 0; rep < 16; ++rep) {
      int k = rep * 16 + (tid >> 4), n = tid & 15;
      lt[k * 17 + n] = W[k * 512 + 16 * t + n];
    }
    __syncthreads();
    bf16x8 o0, o1;
    const int ol = tid * 16;
    #pragma unroll
    for (int s = 0; s < 16; ++s) {
      int o = ol + s;
      int ks = (o >> 9) & 7, g2 = (o >> 7) & 3, n16 = (o >> 3) & 15, j = o & 7;
      int k = 32 * ks + 8 * g2 + j;
      short v = f2bf(lt[k * 17 + n16]);
      if (s < 8) o0[s] = v; else o1[s - 8] = v;
    }
    short* dst = wt + 16384 + m * 131072 + t * 4096 + ol;
    *(bf16x8*)dst = o0;
    *(bf16x8*)(dst + 8) = o1;
  } else {
    const int t = bid - 96;
    #pragma unroll
    for (int rep = 0; rep < 4; ++rep) {
      int k = rep * 16 + (tid >> 4), n = tid & 15;
      lt[k * 17 + n] = Ws[k * 256 + 16 * t + n];
    }
    __syncthreads();
    short4 o;
    const int ol = tid * 4;
    #pragma unroll
    for (int s = 0; s < 4; ++s) {
      int o_ = ol + s;
      int ks1 = (o_ >> 9) & 1, g2 = (o_ >> 7) & 3, n16 = (o_ >> 3) & 15, j = o_ & 7;
      int k = 32 * ks1 + 8 * g2 + j;
      short v = f2bf(lt[k * 17 + n16]);
      if (s == 0) o.x = v; else if (s == 1) o.y = v; else if (s == 2) o.z = v; else o.w = v;
    }
    *(short4*)(wt + t * 1024 + ol) = o;
  }
}

// A-frag (16x32) from swizzled shared activ: elem (e,k) at
// activ[e*256 + ((k>>3 ^ (e&15))<<3 | (k&7))]; frag k = 32ks+8lg+j.
static __device__ __forceinline__ bf16x8 ld_a(const short* activ,
                                              int e, int ks, int lg) {
  return *(const bf16x8*)(activ + e * 256 + ((((4 * ks + lg) ^ (e & 15))) << 3));
}

// qk for one mh half (rows 16*(4*MH+m4)+l15): 4 MFMA per A-frag load.
#define QK_MH(MH)                                                              \
  {                                                                            \
    f32x4 aq0[4], aq1[4], ak0[4], ak1[4];                                      \
    _Pragma("unroll") for (int i = 0; i < 4; ++i) {                            \
      aq0[i] = splat4(biq0); aq1[i] = splat4(biq1);                            \
      ak0[i] = splat4(bik0); ak1[i] = splat4(bik1);                            \
    }                                                                          \
    _Pragma("unroll") for (int ks = 0; ks < 8; ++ks) {                         \
      bf16x8 bqf0 = *(const bf16x8*)(baq0 + ks * 512);                         \
      bf16x8 bqf1 = *(const bf16x8*)(baq1 + ks * 512);                         \
      bf16x8 bkf0 = *(const bf16x8*)(bak0 + ks * 512);                         \
      bf16x8 bkf1 = *(const bf16x8*)(bak1 + ks * 512);                         \
      _Pragma("unroll") for (int m4 = 0; m4 < 4; ++m4) {                       \
        bf16x8 af = ld_a(activ, 16 * (4 * (MH) + m4) + l15, ks, lg);           \
        aq0[m4] = __builtin_amdgcn_mfma_f32_16x16x32_bf16(af, bqf0, aq0[m4], 0, 0, 0); \
        aq1[m4] = __builtin_amdgcn_mfma_f32_16x16x32_bf16(af, bqf1, aq1[m4], 0, 0, 0); \
        ak0[m4] = __builtin_amdgcn_mfma_f32_16x16x32_bf16(af, bkf0, ak0[m4], 0, 0, 0); \
        ak1[m4] = __builtin_amdgcn_mfma_f32_16x16x32_bf16(af, bkf1, ak1[m4], 0, 0, 0); \
      }                                                                        \
    }                                                                          \
    _Pragma("unroll") for (int m4 = 0; m4 < 4; ++m4)                           \
      _Pragma("unroll") for (int r = 0; r < 4; ++r)                            \
        pl[(4 * (MH) + m4) * 4 + r] +=                                         \
            aq0[m4][r] * ak0[m4][r] + aq1[m4][r] * ak1[m4][r];                 \
  }

// v for one mh half: all 4 d-cols at once, 4 MFMA per A-frag load.
#define V_MH(MH)                                                               \
  {                                                                            \
    f32x4 av0[4], av1[4], av2[4], av3[4];                                      \
    _Pragma("unroll") for (int i = 0; i < 4; ++i) {                            \
      av0[i] = splat4(biv0); av1[i] = splat4(biv1);                            \
      av2[i] = splat4(biv2); av3[i] = splat4(biv3);                            \
    }                                                                          \
    _Pragma("unroll") for (int ks = 0; ks < 8; ++ks) {                         \
      bf16x8 bvf0 = *(const bf16x8*)(bav0 + ks * 512);                         \
      bf16x8 bvf1 = *(const bf16x8*)(bav0 + 4096 + ks * 512);                  \
      bf16x8 bvf2 = *(const bf16x8*)(bav0 + 8192 + ks * 512);                  \
      bf16x8 bvf3 = *(const bf16x8*)(bav0 + 12288 + ks * 512);                 \
      _Pragma("unroll") for (int m4 = 0; m4 < 4; ++m4) {                       \
        bf16x8 af = ld_a(activ, 16 * (4 * (MH) + m4) + l15, ks, lg);           \
        av0[m4] = __builtin_amdgcn_mfma_f32_16x16x32_bf16(af, bvf0, av0[m4], 0, 0, 0); \
        av1[m4] = __builtin_amdgcn_mfma_f32_16x16x32_bf16(af, bvf1, av1[m4], 0, 0, 0); \
        av2[m4] = __builtin_amdgcn_mfma_f32_16x16x32_bf16(af, bvf2, av2[m4], 0, 0, 0); \
        av3[m4] = __builtin_amdgcn_mfma_f32_16x16x32_bf16(af, bvf3, av3[m4], 0, 0, 0); \
      }                                                                        \
    }                                                                          \
    _Pragma("unroll") for (int m4 = 0; m4 < 4; ++m4)                           \
      _Pragma("unroll") for (int r = 0; r < 4; ++r) {                          \
        float a = pl[(4 * (MH) + m4) * 4 + r];                                 \
        t0 += a * av0[m4][r]; t1 += a * av1[m4][r];                            \
        t2 += a * av2[m4][r]; t3 += a * av3[m4][r];                            \
      }                                                                        \
  }

__global__ __launch_bounds__(256, 2) void fused_kernel(
    const float* __restrict__ x,
    const float* __restrict__ bsub, const float* __restrict__ bq,
    const float* __restrict__ bk,   const float* __restrict__ bv,
    const short* __restrict__ wt,   float* __restrict__ out)
{
  __shared__ short activ[128 * 256];   // 64KB, XOR-swizzled (16B granule)
  __shared__ float smask[128];

  const int b   = blockIdx.x;
  const int tid = threadIdx.x;
  const int w   = tid >> 6;       // wave 0..3
  const int l   = tid & 63;
  const int l15 = l & 15;
  const int lg  = l >> 4;

  const float* xb  = x + (size_t)b * XROW;
  const short* wts = wt;
  const short* wtq = wt + 16384;
  const short* wtk = wtq + 131072;
  const short* wtv = wtk + 131072;

  if (tid < 128) smask[tid] = xb[MASK_OFF + tid];

  // ---------------- GEMM1: activ = xe @ Wsub + bsub ----------------------
  // wave w owns rows 32w..32w+31 (two m-tiles).
  {
    bf16x8 a1[2][2];
    #pragma unroll
    for (int mt = 0; mt < 2; ++mt)
      #pragma unroll
      for (int ks1 = 0; ks1 < 2; ++ks1) {
        int e = 32 * w + 16 * mt + l15;
        const float* p = xb + e * 64 + 32 * ks1 + 8 * lg;
        float4 f0 = *(const float4*)p;
        float4 f1 = *(const float4*)(p + 4);
        bf16x8 t;
        t[0] = f2bf(f0.x); t[1] = f2bf(f0.y); t[2] = f2bf(f0.z); t[3] = f2bf(f0.w);
        t[4] = f2bf(f1.x); t[5] = f2bf(f1.y); t[6] = f2bf(f1.z); t[7] = f2bf(f1.w);
        a1[mt][ks1] = t;
      }
    #pragma unroll 1
    for (int t = 0; t < 16; ++t) {
      f32x4 acc0 = splat4(bsub[16 * t + l15]);
      f32x4 acc1 = acc0;
      #pragma unroll
      for (int ks1 = 0; ks1 < 2; ++ks1) {
        bf16x8 bfw = *(const bf16x8*)(wts + t * 1024 + ks1 * 512 + lg * 128 + l15 * 8);
        acc0 = __builtin_amdgcn_mfma_f32_16x16x32_bf16(a1[0][ks1], bfw, acc0, 0, 0, 0);
        acc1 = __builtin_amdgcn_mfma_f32_16x16x32_bf16(a1[1][ks1], bfw, acc1, 0, 0, 0);
      }
      #pragma unroll
      for (int r = 0; r < 4; ++r) {
        int col = 16 * t + l15;
        int e0  = 32 * w + 4 * lg + r;
        int e1  = 32 * w + 16 + 4 * lg + r;
        activ[e0 * 256 + ((((col >> 3) ^ (e0 & 15)) << 3) | (col & 7))] = f2bf(acc0[r]);
        activ[e1 * 256 + ((((col >> 3) ^ (e1 & 15)) << 3) | (col & 7))] = f2bf(acc1[r]);
      }
    }
  }
  __syncthreads();   // the only barrier

  // elem_frac (exact: mask is 0/1) — wave 0 lanes
  if (tid < 64) {
    float s = smask[tid] + smask[tid + 64];
    #pragma unroll
    for (int off = 32; off > 0; off >>= 1) s += __shfl_xor(s, off);
    if (tid == 0) out[b * 513 + 512] = s * (1.f / 128.f);
  }

  // lane's mask bits for its 32 rows e = 16mt + 4lg + r  (i = mt*4+r);
  // same mask for every head.
  unsigned mm = 0;
  #pragma unroll
  for (int mt = 0; mt < 8; ++mt)
    #pragma unroll
    for (int r = 0; r < 4; ++r)
      if (smask[16 * mt + 4 * lg + r] > 0.f) mm |= (1u << (mt * 4 + r));

  // ---------------- two heads per wave, sequential ------------------------
  #pragma unroll 1
  for (int hi = 0; hi < 2; ++hi) {
    const int h = w + 4 * hi;

    // ---- qk: scores for all 128 rows ----
    float pl[32];
    #pragma unroll
    for (int i = 0; i < 32; ++i) pl[i] = 0.f;

    #pragma unroll 1
    for (int ntp = 0; ntp < 2; ++ntp) {
      const short* baq0 = wtq + (4 * h + 2 * ntp) * 4096 + lg * 128 + l15 * 8;
      const short* baq1 = baq0 + 4096;
      const short* bak0 = wtk + (4 * h + 2 * ntp) * 4096 + lg * 128 + l15 * 8;
      const short* bak1 = bak0 + 4096;
      float biq0 = bq[h * 64 + 32 * ntp + l15];
      float biq1 = bq[h * 64 + 32 * ntp + 16 + l15];
      float bik0 = bk[h * 64 + 32 * ntp + l15];
      float bik1 = bk[h * 64 + 32 * ntp + 16 + l15];
      QK_MH(0)
      QK_MH(1)
    }
    // reduce d-partials over the 16 d-lanes; scale 1/sqrt(64)
    #pragma unroll
    for (int i = 0; i < 32; ++i) {
      float s = pl[i];
      s += __shfl_xor(s, 1);
      s += __shfl_xor(s, 2);
      s += __shfl_xor(s, 4);
      s += __shfl_xor(s, 8);
      pl[i] = s * 0.125f;
    }

    // ---- masked softmax, fully wave-local ----
    float zmax = 0.f;  // relu floor
    #pragma unroll
    for (int i = 0; i < 32; ++i)
      zmax = fmaxf(zmax, ((mm >> i) & 1) ? pl[i] : 0.f);
    zmax = fmaxf(zmax, __shfl_xor(zmax, 16));
    zmax = fmaxf(zmax, __shfl_xor(zmax, 32));

    float esum = 0.f;
    #pragma unroll
    for (int i = 0; i < 32; ++i) {
      float ev = ((mm >> i) & 1) ? __expf(pl[i] - zmax) : 0.f;
      pl[i] = ev;
      esum += ev;
    }
    esum += __shfl_xor(esum, 16);
    esum += __shfl_xor(esum, 32);
    float inv = 1.f / (esum + 1.f);
    #pragma unroll
    for (int i = 0; i < 32; ++i) pl[i] *= inv;

    // ---- v: project + attn-weighted pool, direct out ----
    {
      const short* bav0 = wtv + (4 * h) * 4096 + lg * 128 + l15 * 8;
      float biv0 = bv[h * 64 + l15];
      float biv1 = bv[h * 64 + 16 + l15];
      float biv2 = bv[h * 64 + 32 + l15];
      float biv3 = bv[h * 64 + 48 + l15];
      float t0 = 0.f, t1 = 0.f, t2 = 0.f, t3 = 0.f;
      V_MH(0)
      V_MH(1)
      t0 += __shfl_xor(t0, 16); t0 += __shfl_xor(t0, 32);
      t1 += __shfl_xor(t1, 16); t1 += __shfl_xor(t1, 32);
      t2 += __shfl_xor(t2, 16); t2 += __shfl_xor(t2, 32);
      t3 += __shfl_xor(t3, 16); t3 += __shfl_xor(t3, 32);
      if (lg == 0) {
        out[b * 513 + h * 64 + l15]      = t0;
        out[b * 513 + h * 64 + 16 + l15] = t1;
        out[b * 513 + h * 64 + 32 + l15] = t2;
        out[b * 513 + h * 64 + 48 + l15] = t3;
      }
    }
  }
}

extern "C" void kernel_launch(void* const* d_in, const int* in_sizes, int n_in,
                              void* d_out, int out_size, void* d_ws, size_t ws_size,
                              hipStream_t stream) {
  (void)in_sizes; (void)n_in; (void)out_size; (void)ws_size;
  const float* x    = (const float*)d_in[0];
  const float* Wsub = (const float*)d_in[1];
  const float* bsub = (const float*)d_in[2];
  const float* Wq   = (const float*)d_in[3];
  const float* bq   = (const float*)d_in[4];
  const float* Wk   = (const float*)d_in[5];
  const float* bk   = (const float*)d_in[6];
  const float* Wv   = (const float*)d_in[7];
  const float* bv   = (const float*)d_in[8];
  float* out = (float*)d_out;
  short* wt  = (short*)d_ws;   // 800 KB used

  prep_weights<<<112, 256, 0, stream>>>(Wsub, Wq, Wk, Wv, wt);
  fused_kernel<<<1024, 256, 0, stream>>>(x, bsub, bq, bk, bv, wt, out);
}